// Round 1
// baseline (189.582 us; speedup 1.0000x reference)
//
#include <hip/hip_runtime.h>

// ---------------- static config (matches reference) ----------------
static constexpr int GS0 = 2048, GS1 = 1024, GS2 = 512;
static constexpr size_t BYTE_OFF0 = 0;
static constexpr size_t BYTE_OFF1 = (size_t)GS0 * GS0;                       // 4194304
static constexpr size_t BYTE_OFF2 = BYTE_OFF1 + (size_t)GS1 * GS1;           // 5242880
static constexpr size_t BYTE_TOT  = BYTE_OFF2 + (size_t)GS2 * GS2;           // 5505024

static constexpr size_t BIT_OFF0 = 0;
static constexpr size_t BIT_OFF1 = (size_t)GS0 * GS0 / 8;                    // 524288
static constexpr size_t BIT_OFF2 = BIT_OFF1 + (size_t)GS1 * GS1 / 8;         // 655360
static constexpr size_t BIT_TOT  = BIT_OFF2 + (size_t)GS2 * GS2 / 8;         // 688128

__device__ __forceinline__ int dev_gs(int r) { return r == 0 ? GS0 : (r == 1 ? GS1 : GS2); }

// ---------------- scatter: mark occupied cells ----------------
template <bool BYTES>
__global__ void mpc_scatter(const float2* __restrict__ pts, int n,
                            const float* __restrict__ psz,   // [3][2]
                            const float* __restrict__ pmin,  // [2]
                            unsigned char* __restrict__ ws) {
    const float minx = pmin[0], miny = pmin[1];
    float psx[3], psy[3];
#pragma unroll
    for (int r = 0; r < 3; ++r) { psx[r] = psz[2 * r]; psy[r] = psz[2 * r + 1]; }

    int i = blockIdx.x * blockDim.x + threadIdx.x;
    const int stride = gridDim.x * blockDim.x;
    for (; i < n; i += stride) {
        const float2 p = pts[i];
        const float px = p.x - minx;
        const float py = p.y - miny;
#pragma unroll
        for (int r = 0; r < 3; ++r) {
            const int g = dev_gs(r);
            int cx = (int)floorf(px / psx[r]);
            int cy = (int)floorf(py / psy[r]);
            cx = min(max(cx, 0), g - 1);
            cy = min(max(cy, 0), g - 1);
            const size_t idx = (size_t)cy * (size_t)g + (size_t)cx;
            if (BYTES) {
                const size_t off = (r == 0 ? BYTE_OFF0 : (r == 1 ? BYTE_OFF1 : BYTE_OFF2));
                ws[off + idx] = (unsigned char)1;   // idempotent; races all write 1
            } else {
                const size_t off = (r == 0 ? BIT_OFF0 : (r == 1 ? BIT_OFF1 : BIT_OFF2));
                unsigned int* w = (unsigned int*)(ws + off);
                atomicOr(&w[idx >> 5], 1u << (idx & 31));
            }
        }
    }
}

// ---------------- reduce: per-slice occupied count ----------------
// block b in [0,112): b<64 -> res0 slice b; b<96 -> res1; else res2.
// Slice = 32 consecutive rows = contiguous chunk of the linear grid.
// Bytes are 0/1 (byte mode) or bits (bit mode) -> __popc counts both.
template <bool BYTES>
__global__ void mpc_reduce(const unsigned char* __restrict__ ws, float* __restrict__ out) {
    const int b = blockIdx.x;
    int r, s;
    if (b < 64)      { r = 0; s = b; }
    else if (b < 96) { r = 1; s = b - 64; }
    else             { r = 2; s = b - 96; }
    const int g = dev_gs(r);
    const size_t cells = (size_t)32 * (size_t)g;
    const size_t chunk_bytes = BYTES ? cells : (cells >> 3);
    const size_t base =
        (BYTES ? (r == 0 ? BYTE_OFF0 : (r == 1 ? BYTE_OFF1 : BYTE_OFF2))
               : (r == 0 ? BIT_OFF0  : (r == 1 ? BIT_OFF1  : BIT_OFF2)))
        + (size_t)s * chunk_bytes;

    const uint4* p = (const uint4*)(ws + base);
    const int nvec = (int)(chunk_bytes >> 4);
    unsigned int sum = 0;
    for (int i = threadIdx.x; i < nvec; i += blockDim.x) {
        const uint4 v = p[i];
        sum += __popc(v.x) + __popc(v.y) + __popc(v.z) + __popc(v.w);
    }
    // wave64 reduce
#pragma unroll
    for (int o = 32; o > 0; o >>= 1) sum += __shfl_down(sum, o, 64);
    __shared__ unsigned int ssum[4];
    const int wave = threadIdx.x >> 6, lane = threadIdx.x & 63;
    if (lane == 0) ssum[wave] = sum;
    __syncthreads();
    if (threadIdx.x == 0) {
        unsigned int t = 0;
        const int nw = blockDim.x >> 6;
        for (int w = 0; w < nw; ++w) t += ssum[w];
        out[b] = (float)t;
    }
}

extern "C" void kernel_launch(void* const* d_in, const int* in_sizes, int n_in,
                              void* d_out, int out_size, void* d_ws, size_t ws_size,
                              hipStream_t stream) {
    const float2* pts = (const float2*)d_in[0];
    const float*  psz = (const float*)d_in[1];
    const float*  pmn = (const float*)d_in[2];
    float* out = (float*)d_out;
    const int n = in_sizes[0] / 2;

    const bool bytes_mode = (ws_size >= BYTE_TOT);
    const size_t grid_bytes = bytes_mode ? BYTE_TOT : BIT_TOT;

    hipMemsetAsync(d_ws, 0, grid_bytes, stream);

    const int threads = 256;
    int blocks = (n + threads - 1) / threads;
    if (blocks > 8192) blocks = 8192;

    if (bytes_mode) {
        mpc_scatter<true><<<blocks, threads, 0, stream>>>(
            pts, n, psz, pmn, (unsigned char*)d_ws);
        mpc_reduce<true><<<112, 256, 0, stream>>>((const unsigned char*)d_ws, out);
    } else {
        mpc_scatter<false><<<blocks, threads, 0, stream>>>(
            pts, n, psz, pmn, (unsigned char*)d_ws);
        mpc_reduce<false><<<112, 256, 0, stream>>>((const unsigned char*)d_ws, out);
    }
}